// Round 3
// baseline (115.925 us; speedup 1.0000x reference)
//
#include <hip/hip_runtime.h>
#include <math.h>

#define NB   4
#define CIN  512
#define HID  64
#define NK   11     // NUM_CLASSES+1
#define H1   60
#define W1p  80
#define P1   4800
#define H2   30
#define W2p  40
#define P2   1200
#define HO   480
#define WOp  640
#define PLANE ((size_t)HO*WOp)                  // 307200
#define SEG_OFF ((size_t)NB*NK*PLANE)           // 13,516,800
#define BBX_OFF (SEG_OFF + (size_t)NB*PLANE)    // 14,745,600

// ws layout in floats
#define WS_WT1 0
#define WS_WT2 32768
#define WS_C1  65536                            // 19200*64 = 1,228,800
#define WS_F2  (WS_C1 + 19200*64)               // 4800*64  =   307,200
#define WS_PRB (WS_F2 + 4800*64)                // 19200*12 =   230,400
#define WS_SEG (WS_PRB + 19200*12)              // 19200 ints

// ---------------- transpose weights: wT[c*64+o] = w[o*512+c] ----------------
__global__ __launch_bounds__(256) void transpose_w(const float* __restrict__ w1,
                                                   const float* __restrict__ w2,
                                                   float* __restrict__ ws) {
    int i = blockIdx.x * 256 + threadIdx.x;   // 0..32767
    if (i >= HID * CIN) return;
    int o = i >> 9;           // /512
    int c = i & 511;
    ws[WS_WT1 + c * HID + o] = w1[i];
    ws[WS_WT2 + c * HID + o] = w2[i];
}

// ---------------- fused conv1x1 GEMM for f1 (300 blocks) and f2 (76 blocks) ----
// 256 threads: wave w owns output rows 16w..16w+15 (wave-uniform weight reads ->
// scalar cache), lane owns 1 pixel. acc[16] regs. x prefetch: 4 rotating chunks
// of 8 channels = 32 channels (~1024 compute cycles) in flight, to cover
// HBM-cold ~900cy load latency at the measured 1.5 waves/SIMD occupancy.
__global__ __launch_bounds__(256) void conv_gemm(const float* __restrict__ f1,
                                                 const float* __restrict__ f2,
                                                 const float* __restrict__ b1v,
                                                 const float* __restrict__ b2v,
                                                 float* __restrict__ ws) {
    int t = blockIdx.x;
    const float* X; const float* wT; const float* bias; float* Cout;
    int P, px0;
    if (t < 300) {
        int b = t / 75; px0 = (t % 75) * 64;
        X = f1 + (size_t)b * CIN * P1;  P = P1;
        wT = ws + WS_WT1; bias = b1v;
        Cout = ws + WS_C1 + (size_t)b * P1 * 64;
    } else {
        int u = t - 300; int b = u / 19; px0 = (u % 19) * 64;
        X = f2 + (size_t)b * CIN * P2;  P = P2;
        wT = ws + WS_WT2; bias = b2v;
        Cout = ws + WS_F2 + (size_t)b * P2 * 64;
    }
    int lane = threadIdx.x & 63;
    int wv   = threadIdx.x >> 6;
    int row0 = __builtin_amdgcn_readfirstlane(wv << 4);   // 16*wave, SGPR
    int p    = px0 + lane;
    bool okp = p < P;
    int pc   = okp ? p : P - 1;

    const float* Xp = X + pc;
    const float* Wp = wT + row0;

    float acc[16];
#pragma unroll
    for (int r = 0; r < 16; ++r) acc[r] = 0.f;

    float xq[4][8];
#pragma unroll
    for (int j = 0; j < 4; ++j)
#pragma unroll
        for (int i = 0; i < 8; ++i) xq[j][i] = Xp[(size_t)(j * 8 + i) * P];

    // main loop: steps of 32 channels; chunk j computed then immediately
    // refilled with channels c0+32+8j (used 4 chunks ~1024 cycles later)
    for (int c0 = 0; c0 < CIN - 32; c0 += 32) {
#pragma unroll
        for (int j = 0; j < 4; ++j) {
#pragma unroll
            for (int i = 0; i < 8; ++i) {
                const float* wr = Wp + (size_t)(c0 + j * 8 + i) * 64;
                float x = xq[j][i];
#pragma unroll
                for (int r4 = 0; r4 < 4; ++r4) {
                    float4 wq = *(const float4*)(wr + r4 * 4);
                    acc[r4*4+0] = fmaf(x, wq.x, acc[r4*4+0]);
                    acc[r4*4+1] = fmaf(x, wq.y, acc[r4*4+1]);
                    acc[r4*4+2] = fmaf(x, wq.z, acc[r4*4+2]);
                    acc[r4*4+3] = fmaf(x, wq.w, acc[r4*4+3]);
                }
            }
#pragma unroll
            for (int i = 0; i < 8; ++i)
                xq[j][i] = Xp[(size_t)(c0 + 32 + j * 8 + i) * P];
        }
    }
    // epilogue: last 32 channels, no prefetch
    {
        const int c0 = CIN - 32;
#pragma unroll
        for (int j = 0; j < 4; ++j) {
#pragma unroll
            for (int i = 0; i < 8; ++i) {
                const float* wr = Wp + (size_t)(c0 + j * 8 + i) * 64;
                float x = xq[j][i];
#pragma unroll
                for (int r4 = 0; r4 < 4; ++r4) {
                    float4 wq = *(const float4*)(wr + r4 * 4);
                    acc[r4*4+0] = fmaf(x, wq.x, acc[r4*4+0]);
                    acc[r4*4+1] = fmaf(x, wq.y, acc[r4*4+1]);
                    acc[r4*4+2] = fmaf(x, wq.z, acc[r4*4+2]);
                    acc[r4*4+3] = fmaf(x, wq.w, acc[r4*4+3]);
                }
            }
        }
    }

    if (okp) {
        float* op = Cout + (size_t)p * 64 + row0;
#pragma unroll
        for (int r4 = 0; r4 < 4; ++r4) {
            float4 v;
            float a0 = acc[r4*4+0] + bias[row0 + r4*4+0];
            float a1 = acc[r4*4+1] + bias[row0 + r4*4+1];
            float a2 = acc[r4*4+2] + bias[row0 + r4*4+2];
            float a3 = acc[r4*4+3] + bias[row0 + r4*4+3];
            v.x = a0 > 0.f ? a0 : 0.f;
            v.y = a1 > 0.f ? a1 : 0.f;
            v.z = a2 > 0.f ? a2 : 0.f;
            v.w = a3 > 0.f ? a3 : 0.f;
            *(float4*)(op + r4 * 4) = v;
        }
    }
}

// ---------------- head: per 60x80 pixel: add feat2-up, wo conv, softmax, argmax
__global__ __launch_bounds__(256) void head_kernel(const float* __restrict__ wo,
                                                   const float* __restrict__ bo,
                                                   float* __restrict__ ws) {
    __shared__ float swo[NK * 64];
    __shared__ float sbo[NK];
    for (int i = threadIdx.x; i < NK * 64; i += 256) swo[i] = wo[i];
    if (threadIdx.x < NK) sbo[threadIdx.x] = bo[threadIdx.x];
    __syncthreads();

    int p  = blockIdx.x * 256 + threadIdx.x;   // 0..19199
    int b  = p / P1;
    int pb = p % P1;
    int y  = pb / W1p, x = pb % W1p;
    int qp = (y >> 1) * W2p + (x >> 1);
    const float* c1p = ws + WS_C1 + ((size_t)b * P1 + pb) * 64;
    const float* f2p = ws + WS_F2 + ((size_t)b * P2 + qp) * 64;

    float ok[NK];
#pragma unroll
    for (int k = 0; k < NK; ++k) ok[k] = sbo[k];
#pragma unroll
    for (int o4 = 0; o4 < 16; ++o4) {
        float4 c1q = *(const float4*)(c1p + o4 * 4);
        float4 f2q = *(const float4*)(f2p + o4 * 4);
        float co[4] = { c1q.x + f2q.x, c1q.y + f2q.y, c1q.z + f2q.z, c1q.w + f2q.w };
#pragma unroll
        for (int j = 0; j < 4; ++j) {
            int o = o4 * 4 + j;
#pragma unroll
            for (int k = 0; k < NK; ++k) ok[k] = fmaf(co[j], swo[k * 64 + o], ok[k]);
        }
    }
    float m = 0.f;
#pragma unroll
    for (int k = 0; k < NK; ++k) {
        ok[k] = ok[k] > 0.f ? ok[k] : 0.f;          // relu(out)
        if (ok[k] > m) m = ok[k];
    }
    float e[NK], sum = 0.f;
#pragma unroll
    for (int k = 0; k < NK; ++k) { e[k] = expf(ok[k] - m); sum += e[k]; }
    float inv = 1.f / sum;
    int arg = 0; float best = ok[0];
#pragma unroll
    for (int k = 1; k < NK; ++k) { if (ok[k] > best) { best = ok[k]; arg = k; } }

    float* pr = ws + WS_PRB + (size_t)p * 12;
#pragma unroll
    for (int k = 0; k < NK; ++k) pr[k] = e[k] * inv;
    pr[11] = (float)arg;
    ((int*)(ws + WS_SEG))[p] = arg;
}

// ---------------- upsample 8x: pure streaming replicate-store ----------------
__global__ __launch_bounds__(256) void upsample_kernel(const float* __restrict__ ws,
                                                       float* __restrict__ out) {
    const float* prb = ws + WS_PRB;
    unsigned total4 = (unsigned)((SEG_OFF + (size_t)NB * PLANE) / 4);  // 3,686,400
    unsigned step = gridDim.x * 256;
    for (unsigned i4 = blockIdx.x * 256 + threadIdx.x; i4 < total4; i4 += step) {
        unsigned f = i4 * 4;
        float v;
        if (f < (unsigned)SEG_OFF) {
            unsigned plane = f / (unsigned)PLANE;      // 0..43
            unsigned r = f - plane * (unsigned)PLANE;
            unsigned b = plane / NK, k = plane - b * NK;
            unsigned y = r / WOp, x = r - y * WOp;
            unsigned p = b * P1 + (y >> 3) * W1p + (x >> 3);
            v = prb[p * 12 + k];
        } else {
            unsigned g = f - (unsigned)SEG_OFF;
            unsigned b = g / (unsigned)PLANE;
            unsigned r = g - b * (unsigned)PLANE;
            unsigned y = r / WOp, x = r - y * WOp;
            unsigned p = b * P1 + (y >> 3) * W1p + (x >> 3);
            v = prb[p * 12 + 11];
        }
        *(float4*)(out + f) = make_float4(v, v, v, v);
    }
}

// ---------------- bbox: per-(batch,class) min/max/count over 60x80 seg ----------------
__global__ __launch_bounds__(256) void bbx_kernel(const float* __restrict__ ws,
                                                  float* __restrict__ out) {
    __shared__ int cnt[10], xmn[10], xmx[10], ymn[10], ymx[10];
    int b = blockIdx.x;
    int t = threadIdx.x;
    if (t < 10) { cnt[t] = 0; xmn[t] = 1 << 30; xmx[t] = -1; ymn[t] = 1 << 30; ymx[t] = -1; }
    __syncthreads();
    const int* seg = (const int*)(ws + WS_SEG) + b * P1;
    for (int p = t; p < P1; p += 256) {
        int s = seg[p];
        if (s >= 1 && s <= 9) {
            int y = p / W1p, x = p % W1p;
            atomicAdd(&cnt[s], 1);
            atomicMin(&xmn[s], x); atomicMax(&xmx[s], x);
            atomicMin(&ymn[s], y); atomicMax(&ymx[s], y);
        }
    }
    __syncthreads();
    if (t < 9) {
        int c = t + 1;
        bool valid = cnt[c] * 64 >= 500;    // upsampled count = 64*count
        float r[6];
        if (valid) {
            r[0] = (float)b;
            r[1] = (float)(xmn[c] * 8);
            r[2] = (float)(ymn[c] * 8);
            r[3] = (float)(xmx[c] * 8 + 7);
            r[4] = (float)(ymx[c] * 8 + 7);
            r[5] = (float)c;
        } else {
            for (int i = 0; i < 6; ++i) r[i] = -1.f;
        }
        float* row = out + BBX_OFF + (size_t)(b * 9 + t) * 6;
        for (int i = 0; i < 6; ++i) row[i] = r[i];
    }
}

extern "C" void kernel_launch(void* const* d_in, const int* in_sizes, int n_in,
                              void* d_out, int out_size, void* d_ws, size_t ws_size,
                              hipStream_t stream) {
    const float* f1 = (const float*)d_in[0];
    const float* f2 = (const float*)d_in[1];
    const float* w1 = (const float*)d_in[2];
    const float* b1 = (const float*)d_in[3];
    const float* w2 = (const float*)d_in[4];
    const float* b2 = (const float*)d_in[5];
    const float* wo = (const float*)d_in[6];
    const float* bo = (const float*)d_in[7];
    float* ws  = (float*)d_ws;
    float* out = (float*)d_out;

    transpose_w<<<128, 256, 0, stream>>>(w1, w2, ws);
    conv_gemm<<<376, 256, 0, stream>>>(f1, f2, b1, b2, ws);
    head_kernel<<<75, 256, 0, stream>>>(wo, bo, ws);
    upsample_kernel<<<2048, 256, 0, stream>>>(ws, out);
    bbx_kernel<<<NB, 256, 0, stream>>>(ws, out);
}

// Round 4
// 78.711 us; speedup vs baseline: 1.4728x; 1.4728x over previous
//
#include <hip/hip_runtime.h>
#include <math.h>

#define NB   4
#define CIN  512
#define HID  64
#define NK   11     // NUM_CLASSES+1
#define H1   60
#define W1p  80
#define P1   4800
#define H2   30
#define W2p  40
#define P2   1200
#define HO   480
#define WOp  640
#define PLANE ((size_t)HO*WOp)                  // 307200
#define SEG_OFF ((size_t)NB*NK*PLANE)           // 13,516,800
#define BBX_OFF (SEG_OFF + (size_t)NB*PLANE)    // 14,745,600

// ws layout in floats
#define WS_WT1 0
#define WS_WT2 32768
#define WS_C1  65536                            // 19200*64 = 1,228,800
#define WS_F2  (WS_C1 + 19200*64)               // 4800*64  =   307,200
#define WS_PRB (WS_F2 + 4800*64)                // 19200*12 =   230,400
#define WS_SEG (WS_PRB + 19200*12)              // 19200 ints

// ---------------- transpose weights: wT[c*64+o] = w[o*512+c] ----------------
__global__ __launch_bounds__(256) void transpose_w(const float* __restrict__ w1,
                                                   const float* __restrict__ w2,
                                                   float* __restrict__ ws) {
    int i = blockIdx.x * 256 + threadIdx.x;   // 0..32767
    if (i >= HID * CIN) return;
    int o = i >> 9;           // /512
    int c = i & 511;
    ws[WS_WT1 + c * HID + o] = w1[i];
    ws[WS_WT2 + c * HID + o] = w2[i];
}

// ---------------- fused conv1x1 GEMM, 16-wave blocks, 4-way channel split ----
// Block = 1024 threads = 16 waves. Wave w: channel group cg=w>>2 (128 ch),
// row group rg=w&3 (rows 16*rg..16*rg+15). Lane = 1 pixel of a 64-px tile.
// Channel groups 1-3 write partial acc to LDS; group 0 reduces + bias + relu
// + store. 6016 waves total -> ~5.9 waves/SIMD (TLP hides HBM latency; the
// previous 4-wave blocks gave only 1.47 waves/SIMD = 14% occupancy).
__global__ __launch_bounds__(1024) void conv_gemm(const float* __restrict__ f1,
                                                  const float* __restrict__ f2,
                                                  const float* __restrict__ wt1,
                                                  const float* __restrict__ wt2,
                                                  const float* __restrict__ b1v,
                                                  const float* __restrict__ b2v,
                                                  float* __restrict__ c1o,
                                                  float* __restrict__ f2o) {
    __shared__ float red[3][64][64];   // [cg-1][row][pixel-lane], 48 KB
    int t = blockIdx.x;
    const float* X; const float* wT; const float* bias; float* Cout;
    int P, px0;
    if (t < 300) {
        int b = t / 75; px0 = (t % 75) * 64;
        X = f1 + (size_t)b * CIN * P1;  P = P1;
        wT = wt1; bias = b1v;
        Cout = c1o + (size_t)b * P1 * 64;
    } else {
        int u = t - 300; int b = u / 19; px0 = (u % 19) * 64;
        X = f2 + (size_t)b * CIN * P2;  P = P2;
        wT = wt2; bias = b2v;
        Cout = f2o + (size_t)b * P2 * 64;
    }
    int lane  = threadIdx.x & 63;
    int wv    = threadIdx.x >> 6;                          // 0..15
    int row0  = __builtin_amdgcn_readfirstlane((wv & 3) << 4);
    int cbase = __builtin_amdgcn_readfirstlane((wv >> 2) << 7);
    int cg    = wv >> 2;
    int p     = px0 + lane;
    bool okp  = p < P;
    int pc    = okp ? p : P - 1;

    const float* Xp = X + (size_t)cbase * P + pc;
    const float* Wp = wT + (size_t)cbase * 64 + row0;

    float acc[16];
#pragma unroll
    for (int r = 0; r < 16; ++r) acc[r] = 0.f;

    float xa[8], xb[8];
#pragma unroll
    for (int i = 0; i < 8; ++i) xa[i] = Xp[(size_t)i * P];

    for (int c0 = 0; c0 < 128; c0 += 8) {
        if (c0 + 8 < 128) {
#pragma unroll
            for (int i = 0; i < 8; ++i) xb[i] = Xp[(size_t)(c0 + 8 + i) * P];
        }
#pragma unroll
        for (int i = 0; i < 8; ++i) {
            const float* wr = Wp + (size_t)(c0 + i) * 64;
            float x = xa[i];
#pragma unroll
            for (int r4 = 0; r4 < 4; ++r4) {
                float4 wq = *(const float4*)(wr + r4 * 4);
                acc[r4*4+0] = fmaf(x, wq.x, acc[r4*4+0]);
                acc[r4*4+1] = fmaf(x, wq.y, acc[r4*4+1]);
                acc[r4*4+2] = fmaf(x, wq.z, acc[r4*4+2]);
                acc[r4*4+3] = fmaf(x, wq.w, acc[r4*4+3]);
            }
        }
#pragma unroll
        for (int i = 0; i < 8; ++i) xa[i] = xb[i];
    }

    if (cg > 0) {
#pragma unroll
        for (int r = 0; r < 16; ++r) red[cg - 1][row0 + r][lane] = acc[r];
    }
    __syncthreads();
    if (cg == 0 && okp) {
        float* op = Cout + (size_t)p * 64 + row0;
#pragma unroll
        for (int r4 = 0; r4 < 4; ++r4) {
            float v[4];
#pragma unroll
            for (int j = 0; j < 4; ++j) {
                int r = r4 * 4 + j;
                float a = acc[r] + red[0][row0 + r][lane] + red[1][row0 + r][lane]
                        + red[2][row0 + r][lane] + bias[row0 + r];
                v[j] = a > 0.f ? a : 0.f;
            }
            *(float4*)(op + r4 * 4) = make_float4(v[0], v[1], v[2], v[3]);
        }
    }
}

// ---------------- head: per 60x80 pixel: add feat2-up, wo conv, softmax, argmax
__global__ __launch_bounds__(256) void head_kernel(const float* __restrict__ wo,
                                                   const float* __restrict__ bo,
                                                   float* __restrict__ ws) {
    __shared__ float swo[NK * 64];
    __shared__ float sbo[NK];
    for (int i = threadIdx.x; i < NK * 64; i += 256) swo[i] = wo[i];
    if (threadIdx.x < NK) sbo[threadIdx.x] = bo[threadIdx.x];
    __syncthreads();

    int p  = blockIdx.x * 256 + threadIdx.x;   // 0..19199
    int b  = p / P1;
    int pb = p % P1;
    int y  = pb / W1p, x = pb % W1p;
    int qp = (y >> 1) * W2p + (x >> 1);
    const float* c1p = ws + WS_C1 + ((size_t)b * P1 + pb) * 64;
    const float* f2p = ws + WS_F2 + ((size_t)b * P2 + qp) * 64;

    float ok[NK];
#pragma unroll
    for (int k = 0; k < NK; ++k) ok[k] = sbo[k];
#pragma unroll
    for (int o4 = 0; o4 < 16; ++o4) {
        float4 c1q = *(const float4*)(c1p + o4 * 4);
        float4 f2q = *(const float4*)(f2p + o4 * 4);
        float co[4] = { c1q.x + f2q.x, c1q.y + f2q.y, c1q.z + f2q.z, c1q.w + f2q.w };
#pragma unroll
        for (int j = 0; j < 4; ++j) {
            int o = o4 * 4 + j;
#pragma unroll
            for (int k = 0; k < NK; ++k) ok[k] = fmaf(co[j], swo[k * 64 + o], ok[k]);
        }
    }
    float m = 0.f;
#pragma unroll
    for (int k = 0; k < NK; ++k) {
        ok[k] = ok[k] > 0.f ? ok[k] : 0.f;          // relu(out)
        if (ok[k] > m) m = ok[k];
    }
    float e[NK], sum = 0.f;
#pragma unroll
    for (int k = 0; k < NK; ++k) { e[k] = expf(ok[k] - m); sum += e[k]; }
    float inv = 1.f / sum;
    int arg = 0; float best = ok[0];
#pragma unroll
    for (int k = 1; k < NK; ++k) { if (ok[k] > best) { best = ok[k]; arg = k; } }

    float* pr = ws + WS_PRB + (size_t)p * 12;
#pragma unroll
    for (int k = 0; k < NK; ++k) pr[k] = e[k] * inv;
    pr[11] = (float)arg;
    ((int*)(ws + WS_SEG))[p] = arg;
}

// ---------------- upsample 8x: pure streaming replicate-store ----------------
__global__ __launch_bounds__(256) void upsample_kernel(const float* __restrict__ ws,
                                                       float* __restrict__ out) {
    const float* prb = ws + WS_PRB;
    unsigned total4 = (unsigned)((SEG_OFF + (size_t)NB * PLANE) / 4);  // 3,686,400
    unsigned step = gridDim.x * 256;
    for (unsigned i4 = blockIdx.x * 256 + threadIdx.x; i4 < total4; i4 += step) {
        unsigned f = i4 * 4;
        float v;
        if (f < (unsigned)SEG_OFF) {
            unsigned plane = f / (unsigned)PLANE;      // 0..43
            unsigned r = f - plane * (unsigned)PLANE;
            unsigned b = plane / NK, k = plane - b * NK;
            unsigned y = r / WOp, x = r - y * WOp;
            unsigned p = b * P1 + (y >> 3) * W1p + (x >> 3);
            v = prb[p * 12 + k];
        } else {
            unsigned g = f - (unsigned)SEG_OFF;
            unsigned b = g / (unsigned)PLANE;
            unsigned r = g - b * (unsigned)PLANE;
            unsigned y = r / WOp, x = r - y * WOp;
            unsigned p = b * P1 + (y >> 3) * W1p + (x >> 3);
            v = prb[p * 12 + 11];
        }
        *(float4*)(out + f) = make_float4(v, v, v, v);
    }
}

// ---------------- bbox: per-(batch,class) min/max/count over 60x80 seg ----------------
__global__ __launch_bounds__(256) void bbx_kernel(const float* __restrict__ ws,
                                                  float* __restrict__ out) {
    __shared__ int cnt[10], xmn[10], xmx[10], ymn[10], ymx[10];
    int b = blockIdx.x;
    int t = threadIdx.x;
    if (t < 10) { cnt[t] = 0; xmn[t] = 1 << 30; xmx[t] = -1; ymn[t] = 1 << 30; ymx[t] = -1; }
    __syncthreads();
    const int* seg = (const int*)(ws + WS_SEG) + b * P1;
    for (int p = t; p < P1; p += 256) {
        int s = seg[p];
        if (s >= 1 && s <= 9) {
            int y = p / W1p, x = p % W1p;
            atomicAdd(&cnt[s], 1);
            atomicMin(&xmn[s], x); atomicMax(&xmx[s], x);
            atomicMin(&ymn[s], y); atomicMax(&ymx[s], y);
        }
    }
    __syncthreads();
    if (t < 9) {
        int c = t + 1;
        bool valid = cnt[c] * 64 >= 500;    // upsampled count = 64*count
        float r[6];
        if (valid) {
            r[0] = (float)b;
            r[1] = (float)(xmn[c] * 8);
            r[2] = (float)(ymn[c] * 8);
            r[3] = (float)(xmx[c] * 8 + 7);
            r[4] = (float)(ymx[c] * 8 + 7);
            r[5] = (float)c;
        } else {
            for (int i = 0; i < 6; ++i) r[i] = -1.f;
        }
        float* row = out + BBX_OFF + (size_t)(b * 9 + t) * 6;
        for (int i = 0; i < 6; ++i) row[i] = r[i];
    }
}

extern "C" void kernel_launch(void* const* d_in, const int* in_sizes, int n_in,
                              void* d_out, int out_size, void* d_ws, size_t ws_size,
                              hipStream_t stream) {
    const float* f1 = (const float*)d_in[0];
    const float* f2 = (const float*)d_in[1];
    const float* w1 = (const float*)d_in[2];
    const float* b1 = (const float*)d_in[3];
    const float* w2 = (const float*)d_in[4];
    const float* b2 = (const float*)d_in[5];
    const float* wo = (const float*)d_in[6];
    const float* bo = (const float*)d_in[7];
    float* ws  = (float*)d_ws;
    float* out = (float*)d_out;

    transpose_w<<<128, 256, 0, stream>>>(w1, w2, ws);
    conv_gemm<<<376, 1024, 0, stream>>>(f1, f2,
                                        ws + WS_WT1, ws + WS_WT2,
                                        b1, b2,
                                        ws + WS_C1, ws + WS_F2);
    head_kernel<<<75, 256, 0, stream>>>(wo, bo, ws);
    upsample_kernel<<<2048, 256, 0, stream>>>(ws, out);
    bbx_kernel<<<NB, 256, 0, stream>>>(ws, out);
}